// Round 10
// baseline (67.098 us; speedup 1.0000x reference)
//
#include <hip/hip_runtime.h>

// AffinitySideLoss: B=4, E=12, H=W=512, S=8 offsets, output = 1 float scalar.
// d_in[0] = input_ float32 [4,12,512,512]
// d_in[1] = target int32   [4,1,512,512]
// d_in[2] = offsets int32  [8,2]  (values in [-27,0))
// d_out   = float32 [1]
// d_ws    = per-block partials: float [16][1024]  (64 KB)
//
// R10: 16x64 supertile, DOUBLE-buffered LDS halo, ONE barrier per channel.
// 1024 blocks x 512 threads (8 waves) = 4 blocks/CU, 32 waves/CU possible
// (R9 was grid-capped at 2 blocks/CU with 26 barriers -> serialization-
// bound; R4-R7 direct-load variants were pinned at ~12 TB/s L2/L3 demand).
// Per channel e: issue global->reg loads for e+1, compute e from buf[e&1],
// ds_write e+1 into buf[(e+1)&1], barrier. Reg staging keeps traffic in
// L2/L3 (global_load_lds bypasses MALL - R6/R8 evidence). Demand ~215 MB.

typedef float f2 __attribute__((ext_vector_type(2)));
typedef float f4 __attribute__((ext_vector_type(4)));

#define HWSZ   262144     // 512*512
#define NE     12
#define NC     13         // 12 emb channels + 1 seg channel
#define NS     8
#define TROWS  16
#define TCOLS  64
#define NBLK   1024       // 4 batches x 32 row-tiles x 8 col-tiles
#define HROWS  44         // rows r0-28 .. r0+15
#define HCOLS  92         // cols c0-28 .. c0+63
#define HSZ    (HROWS * HCOLS)   // 4048 floats
#define NCHUNK (HCOLS / 4)       // 23 f4-chunks per halo row
#define NSLOT  (HSZ / 4)         // 1012 f4 slots

__global__ __launch_bounds__(512) void affloss_main(
    const float* __restrict__ emb, const int* __restrict__ seg,
    const int* __restrict__ offs, float* __restrict__ partial) {
  __shared__ f4 buf4[2][NSLOT];         // 2 x 16,192 B = 32,384 B
  __shared__ float red[8][16];

  // XCD swizzle (bijective, 1024 % 8 == 0): contiguous tile band per XCD so
  // neighbor-tile halo overlap (28/44 rows, 28/92 cols) hits that XCD's L2.
  const int bid = blockIdx.x;
  const int nb  = (bid & 7) * (NBLK / 8) + (bid >> 3);
  const int b   = nb >> 8;              // batch 0..3
  const int rem = nb & 255;             // 32 row-tiles x 8 col-tiles
  const int r0  = (rem >> 3) * TROWS;   // 0..496
  const int c0  = (rem & 7) * TCOLS;    // 0..448

  const int tid = threadIdx.x;
  const int tx  = tid & 31;             // f2 col: tile cols 2tx, 2tx+1
  const int row = tid >> 5;             // tile row 0..15
  const int wv  = tid >> 6;             // wave 0..7

  const float* embB = emb + (size_t)b * NE * HWSZ;
  const int*   segB = seg + (size_t)b * HWSZ;

  int soff[NS];                         // halo-space offset per sample
  #pragma unroll
  for (int s = 0; s < NS; ++s)
    soff[s] = offs[2 * s] * HCOLS + offs[2 * s + 1];   // uniform -> scalar

  // Staging geometry: f4 slot -> (halo row rr, 4-col chunk ch).
  // Global row clamps at 0 (replication pad, top only); fully-negative col
  // chunks (c0==0, halo cols < 28) splat col 0. 16B-aligned otherwise.
  int srow[2], sgc[2];
  #pragma unroll
  for (int k = 0; k < 2; ++k) {
    const int slot = tid + k * 512;
    const int rr = slot / NCHUNK;
    const int ch = slot - rr * NCHUNK;
    int gr = r0 - 28 + rr; gr = gr < 0 ? 0 : gr;
    srow[k] = gr * 512;
    sgc[k] = c0 - 28 + 4 * ch;
  }
  const bool has1 = tid < (NSLOT - 512);   // threads 0..499 own a 2nd slot

  auto stage_load = [&](int e, f4* r) {
    const float* p = (e < NE) ? (embB + (size_t)e * HWSZ) : (const float*)segB;
    #pragma unroll
    for (int k = 0; k < 2; ++k) {
      if (k == 1 && !has1) continue;
      const float* rowp = p + srow[k];
      if (sgc[k] >= 0) {
        r[k] = *reinterpret_cast<const f4*>(rowp + sgc[k]);   // 16B aligned
      } else {
        const float v = rowp[0];                              // left-edge splat
        r[k] = f4{v, v, v, v};
      }
    }
  };
  auto stage_write = [&](int bi, const f4* r) {
    buf4[bi][tid] = r[0];                                     // ds_write_b128
    if (has1) buf4[bi][tid + 512] = r[1];
  };

  f2 ssv[NS];
  #pragma unroll
  for (int s = 0; s < NS; ++s) ssv[s] = f2{0.f, 0.f};
  float numa[NS], dena[NS];

  const int cb = (row + 28) * HCOLS + 28 + 2 * tx;   // center px0 halo idx

  f4 r[2];
  stage_load(0, r);
  stage_write(0, r);
  __syncthreads();

  #pragma unroll
  for (int e = 0; e < NC; ++e) {
    if (e + 1 < NC) stage_load(e + 1, r);    // flies under compute below
    const float* bufp = (const float*)buf4[e & 1];

    if (e < NE) {
      const f2 cc = *reinterpret_cast<const f2*>(bufp + cb);
      #pragma unroll
      for (int s = 0; s < NS; ++s) {
        const int a = cb + soff[s];          // stays inside halo by constr.
        f2 sh; sh[0] = bufp[a]; sh[1] = bufp[a + 1];
        const f2 d = cc - sh;
        ssv[s][0] = fmaf(d[0], d[0], ssv[s][0]);
        ssv[s][1] = fmaf(d[1], d[1], ssv[s][1]);
      }
    } else {
      // seg channel (bit container in floats): int compare + dice sums
      const int tc0 = __float_as_int(bufp[cb]);
      const int tc1 = __float_as_int(bufp[cb + 1]);
      #pragma unroll
      for (int s = 0; s < NS; ++s) {
        const int a = cb + soff[s];
        const int t0 = __float_as_int(bufp[a]);
        const int t1 = __float_as_int(bufp[a + 1]);
        float nacc = 0.f, dacc = 0.f;
        {
          const float n  = __builtin_amdgcn_sqrtf(ssv[s][0]);
          const float rc = fmaxf(fmaf(n, -(1.0f / 3.0f), 1.0f), 0.0f);
          const float A  = fmaf(-rc, rc, 1.0f);
          const float ta = (tc0 == t0) ? 0.f : 1.f;
          nacc = fmaf(A, ta, nacc); dacc += fmaf(A, A, ta);
        }
        {
          const float n  = __builtin_amdgcn_sqrtf(ssv[s][1]);
          const float rc = fmaxf(fmaf(n, -(1.0f / 3.0f), 1.0f), 0.0f);
          const float A  = fmaf(-rc, rc, 1.0f);
          const float ta = (tc1 == t1) ? 0.f : 1.f;
          nacc = fmaf(A, ta, nacc); dacc += fmaf(A, A, ta);
        }
        numa[s] = nacc; dena[s] = dacc;
      }
    }

    if (e + 1 < NC) {
      stage_write((e + 1) & 1, r);           // waits only its own vmcnt
      __syncthreads();
    }
  }

  // block reduction: [0..7]=num, [8..15]=den
  float arr[16];
  #pragma unroll
  for (int s = 0; s < NS; ++s) { arr[s] = numa[s]; arr[8 + s] = dena[s]; }
  #pragma unroll
  for (int k = 0; k < 16; ++k) {
    float v = arr[k];
    #pragma unroll
    for (int o = 32; o > 0; o >>= 1) v += __shfl_down(v, o, 64);
    arr[k] = v;
  }
  const int lane = tid & 63;
  __syncthreads();                           // seg compute done everywhere
  if (lane == 0) {
    #pragma unroll
    for (int k = 0; k < 16; ++k) red[wv][k] = arr[k];
  }
  __syncthreads();
  if (tid < 16) {
    float v = 0.f;
    #pragma unroll
    for (int w = 0; w < 8; ++w) v += red[w][tid];
    partial[tid * NBLK + blockIdx.x] = v;    // [channel][block]
  }
}

__global__ __launch_bounds__(1024) void affloss_final(
    const float* __restrict__ partial, float* __restrict__ out) {
  __shared__ double csum[16];
  const int lane = threadIdx.x & 63, wv = threadIdx.x >> 6;  // wv = channel

  double s = 0.0;
  for (int i = lane; i < NBLK; i += 64)
    s += (double)partial[wv * NBLK + i];
  #pragma unroll
  for (int o = 32; o > 0; o >>= 1) s += __shfl_down(s, o, 64);
  if (lane == 0) csum[wv] = s;
  __syncthreads();

  if (threadIdx.x == 0) {
    double total = 0.0;
    #pragma unroll
    for (int c = 0; c < 8; ++c) {
      double num = csum[c];
      double den = csum[8 + c];
      if (den < 1e-7) den = 1e-7;            // maximum(den, EPS)
      total += 1.0 - 2.0 * num / den;
    }
    out[0] = (float)total;
  }
}

extern "C" void kernel_launch(void* const* d_in, const int* in_sizes, int n_in,
                              void* d_out, int out_size, void* d_ws, size_t ws_size,
                              hipStream_t stream) {
  const float* emb  = (const float*)d_in[0];
  const int*   seg  = (const int*)d_in[1];
  const int*   offs = (const int*)d_in[2];
  float* partial = (float*)d_ws;   // 16*1024 floats = 65,536 B

  affloss_main<<<NBLK, 512, 0, stream>>>(emb, seg, offs, partial);
  affloss_final<<<1, 1024, 0, stream>>>(partial, (float*)d_out);
}